// Round 9
// baseline (235.843 us; speedup 1.0000x reference)
//
#include <hip/hip_runtime.h>
#include <stdint.h>

// All buffers f32. Timed window carries ~168 us of harness poison fills
// (877 MB ws fill @ ~131 us + 219 MB out fill @ ~33 us); our 3 dispatches are
// the ~61 us remainder. Config history (dur_us): r4 CSPLIT4 scalar = 233.6 |
// r5 CSPLIT4 = 231.0 | r7 nt+CSPLIT2 = 240.2 | r8 CSPLIT4 vec-loads = 229.0.
// r9: CSPLIT=1 — one thread owns all 64 channels of its 4 cells: canvas read
// once (3.4 MB, was 13.7), feats row read once, 16 independent load-groups of
// ILP to cover the ~900-cyc HBM latency the gather was stalling on.
#define NYv 496
#define NXv 432
#define Cv  64
#define Bv  4
#define PLANE (NYv * NXv)            // 214272 elements per (b,c) plane
#define NVEC (NXv / 4)               // 108 float4 vectors per canvas row
#define ROWS (Bv * NYv)              // 1984 canvas rows
#define UNITS (ROWS * NVEC)          // 214272 vec-units == 837 * 256 exactly

typedef float  f32x4 __attribute__((ext_vector_type(4)));
typedef int    i32x4 __attribute__((ext_vector_type(4)));

// K1: scatter pillar index i into canvas[(b*NY + y)*NX + x].
// Canvas pre-set to -1 (memset 0xFF) so unoccupied cells read <0.
__global__ __launch_bounds__(256) void scatter_idx(const int4* __restrict__ coords,
                                                   int* __restrict__ canvas, int n) {
    int i = blockIdx.x * 256 + threadIdx.x;
    if (i >= n) return;
    int4 c4 = coords[i];             // (b, z, y, x)
    canvas[((size_t)c4.x * NYv + c4.z) * NXv + c4.w] = i;
}

// K2: inverse gather, full-lane exact-cover mapping (837*256 == 214272 units),
// ALL 64 channels per thread. Per thread: one int4 canvas load -> 4 pillar
// indices; then 16 channel-groups, each: one exec-masked f32x4 feats load per
// occupied pillar (contiguous 256B rows, read exactly once device-wide),
// register transpose, 4 coalesced 1KB-per-wave plane stores. 94% of lanes
// skip feats loads via exec mask; 16 groups give deep MLP against ~900-cyc
// HBM miss latency.
__global__ __launch_bounds__(256) void gather_all(const float* __restrict__ feats,
                                                  const int* __restrict__ canvas,
                                                  float* __restrict__ out) {
    int u = blockIdx.x * 256 + (int)threadIdx.x;   // 0..214271
    int g = u / NVEC;                              // canvas row 0..1983
    int v = u - g * NVEC;                          // 0..107
    int b = g / NYv;
    int y = g - b * NYv;

    i32x4 pi = *reinterpret_cast<const i32x4*>(canvas + (size_t)g * NXv + v * 4);
    int p[4] = {pi.x, pi.y, pi.z, pi.w};

    const float* fp[4];
#pragma unroll
    for (int j = 0; j < 4; ++j) fp[j] = feats + (size_t)p[j] * Cv;

    float* outp = out + (size_t)(b * Cv) * PLANE + y * NXv + v * 4;

#pragma unroll
    for (int cg = 0; cg < Cv / 4; ++cg) {          // 16 groups of 4 channels
        f32x4 w[4] = {{0,0,0,0}, {0,0,0,0}, {0,0,0,0}, {0,0,0,0}};
#pragma unroll
        for (int j = 0; j < 4; ++j) {
            if (p[j] >= 0)                         // exec-masked vector load
                w[j] = *reinterpret_cast<const f32x4*>(fp[j] + cg * 4);
        }
#pragma unroll
        for (int k = 0; k < 4; ++k) {              // transpose: channel k of group
            f32x4 f;
            f.x = w[0][k]; f.y = w[1][k]; f.z = w[2][k]; f.w = w[3][k];
            *reinterpret_cast<f32x4*>(outp + (size_t)(cg * 4 + k) * PLANE) = f;
        }
    }
}

extern "C" void kernel_launch(void* const* d_in, const int* in_sizes, int n_in,
                              void* d_out, int out_size, void* d_ws, size_t ws_size,
                              hipStream_t stream) {
    const float* feats  = (const float*)d_in[0];   // f32, [N, 64]
    const int*   coords = (const int*)d_in[1];     // int32, [N, 4]
    int n = in_sizes[0] / Cv;                      // 48000 pillars
    float* out    = (float*)d_out;
    int*   canvas = (int*)d_ws;                    // 3.43 MB of ~877 MB ws

    // -1 sentinel (0xAA poison is also negative, but don't rely on it).
    (void)hipMemsetAsync(canvas, 0xFF, (size_t)Bv * PLANE * sizeof(int), stream);

    scatter_idx<<<(n + 255) / 256, 256, 0, stream>>>((const int4*)coords, canvas, n);

    gather_all<<<UNITS / 256, 256, 0, stream>>>(feats, canvas, out);  // 837 blocks
}

// Round 10
// 229.450 us; speedup vs baseline: 1.0279x; 1.0279x over previous
//
#include <hip/hip_runtime.h>
#include <stdint.h>

// All buffers f32. Timed window carries ~169 us of harness poison fills
// (877 MB ws fill @ ~132 us + 219 MB out fill @ ~33 us + input restores);
// our 3 dispatches are the ~60 us remainder (floor ~42 us).
// Config ladder (dur_us): r8 CSPLIT4+vec 229.0 | r5 CSPLIT4 231.0 | r4 233.6
// | r9 CSPLIT1 235.8 | r7 nt+CSPLIT2 240.2. Signal: more TLP wins; nt hurts.
// r10: CSPLIT=8 — 6696 blocks (~26/CU), shortest per-thread tail that still
// amortizes one canvas int4 over 2 vectorized feats load-groups.
#define NYv 496
#define NXv 432
#define Cv  64
#define Bv  4
#define PLANE (NYv * NXv)            // 214272 elements per (b,c) plane
#define NVEC (NXv / 4)               // 108 float4 vectors per canvas row
#define ROWS (Bv * NYv)              // 1984 canvas rows
#define UNITS (ROWS * NVEC)          // 214272 vec-units == 837 * 256 exactly
#define CSPLIT 8
#define CCHUNK (Cv / CSPLIT)         // 8 channels per gather thread

typedef float  f32x4 __attribute__((ext_vector_type(4)));
typedef int    i32x4 __attribute__((ext_vector_type(4)));

// K1: scatter pillar index i into canvas[(b*NY + y)*NX + x].
// Canvas pre-set to -1 (memset 0xFF) so unoccupied cells read <0.
__global__ __launch_bounds__(256) void scatter_idx(const int4* __restrict__ coords,
                                                   int* __restrict__ canvas, int n) {
    int i = blockIdx.x * 256 + threadIdx.x;
    if (i >= n) return;
    int4 c4 = coords[i];             // (b, z, y, x)
    canvas[((size_t)c4.x * NYv + c4.z) * NXv + c4.w] = i;
}

// K2: inverse gather, full-lane exact-cover mapping (837*256 == 214272 units),
// 8 channels per thread. Per thread: one int4 canvas load -> 4 pillar indices;
// then 2 channel-groups, each: one exec-masked f32x4 feats load per occupied
// pillar (94% of lanes skip via exec mask), register transpose, 4 coalesced
// 1KB-per-wave plane stores.
__global__ __launch_bounds__(256) void gather_all(const float* __restrict__ feats,
                                                  const int* __restrict__ canvas,
                                                  float* __restrict__ out) {
    int u = blockIdx.x * 256 + (int)threadIdx.x;   // 0..214271
    int g = u / NVEC;                              // canvas row 0..1983
    int v = u - g * NVEC;                          // 0..107
    int b = g / NYv;
    int y = g - b * NYv;
    int c0 = blockIdx.y * CCHUNK;

    i32x4 pi = *reinterpret_cast<const i32x4*>(canvas + (size_t)g * NXv + v * 4);
    int p[4] = {pi.x, pi.y, pi.z, pi.w};

    float* outp = out + ((size_t)(b * Cv + c0)) * PLANE + y * NXv + v * 4;

#pragma unroll
    for (int cg = 0; cg < CCHUNK / 4; ++cg) {      // 2 groups of 4 channels
        f32x4 w[4] = {{0,0,0,0}, {0,0,0,0}, {0,0,0,0}, {0,0,0,0}};
#pragma unroll
        for (int j = 0; j < 4; ++j) {
            if (p[j] >= 0)                         // exec-masked vector load
                w[j] = *reinterpret_cast<const f32x4*>(
                    feats + (size_t)p[j] * Cv + c0 + cg * 4);
        }
#pragma unroll
        for (int k = 0; k < 4; ++k) {              // transpose: channel k of group
            f32x4 f;
            f.x = w[0][k]; f.y = w[1][k]; f.z = w[2][k]; f.w = w[3][k];
            *reinterpret_cast<f32x4*>(outp + (size_t)(cg * 4 + k) * PLANE) = f;
        }
    }
}

extern "C" void kernel_launch(void* const* d_in, const int* in_sizes, int n_in,
                              void* d_out, int out_size, void* d_ws, size_t ws_size,
                              hipStream_t stream) {
    const float* feats  = (const float*)d_in[0];   // f32, [N, 64]
    const int*   coords = (const int*)d_in[1];     // int32, [N, 4]
    int n = in_sizes[0] / Cv;                      // 48000 pillars
    float* out    = (float*)d_out;
    int*   canvas = (int*)d_ws;                    // 3.43 MB of ~877 MB ws

    // -1 sentinel (0xAA poison is also negative, but don't rely on it).
    (void)hipMemsetAsync(canvas, 0xFF, (size_t)Bv * PLANE * sizeof(int), stream);

    scatter_idx<<<(n + 255) / 256, 256, 0, stream>>>((const int4*)coords, canvas, n);

    dim3 gmain(UNITS / 256, CSPLIT);               // (837, 8) — exact cover
    gather_all<<<gmain, 256, 0, stream>>>(feats, canvas, out);
}